// Round 12
// baseline (271.518 us; speedup 1.0000x reference)
//
#include <hip/hip_runtime.h>
#include <stdint.h>

typedef __attribute__((ext_vector_type(8))) short bf16x8;
typedef __attribute__((ext_vector_type(4))) float f32x4;

__device__ __forceinline__ float bf2f(uint16_t u) {
    union { uint32_t u; float f; } c; c.u = ((uint32_t)u) << 16; return c.f;
}
__device__ __forceinline__ uint16_t f2bf(float f) {
    union { float f; uint32_t u; } c; c.f = f;
    uint32_t r = c.u + 0x7fffu + ((c.u >> 16) & 1u);
    return (uint16_t)(r >> 16);
}
__device__ __forceinline__ uint32_t pk2bf(float a, float b) {
#if __has_builtin(__builtin_amdgcn_cvt_pk_bf16_f32)
    auto v = __builtin_amdgcn_cvt_pk_bf16_f32(a, b);
    uint32_t u; __builtin_memcpy(&u, &v, 4); return u;
#else
    return (uint32_t)f2bf(a) | ((uint32_t)f2bf(b) << 16);
#endif
}
// raw v_exp_f32 (no OCML wrapper); exp2(-huge) -> 0 correctly
__device__ __forceinline__ float fexp2(float x) {
#if __has_builtin(__builtin_amdgcn_exp2f)
    return __builtin_amdgcn_exp2f(x);
#else
    return exp2f(x);
#endif
}

// async global->LDS, 16B/lane; LDS dest must be wave-uniform base + lane*16.
__device__ __forceinline__ void gld_lds16(const uint16_t* g, uint16_t* l) {
    __builtin_amdgcn_global_load_lds(
        (const __attribute__((address_space(1))) void*)g,
        (__attribute__((address_space(3))) void*)l, 16, 0, 0);
}

// Bijective XCD swizzle (T1): XCD c owns a contiguous M-range x all N-tiles,
// so the A panel is fetched once chip-wide and N-sharing blocks co-reside in
// one L2. Requires gridDim.y % 8 == 0. Returns (mtile, ntile).
__device__ __forceinline__ int2 xcd_swz() {
    const int nx = gridDim.x;
    const int ib = blockIdx.y * nx + blockIdx.x;
    const int c = ib & 7, j = ib >> 3;
    const int mpx = gridDim.y >> 3;
    return make_int2(c * mpx + j / nx, j % nx);
}

// ---------------------------------------------------------------------------
// Single fused prep (weights transpose, x convert, bias convert)
// ---------------------------------------------------------------------------
__global__ void prep_all(const float* __restrict__ x,
                         const float* __restrict__ W1, const float* __restrict__ W2,
                         const float* __restrict__ Wq, const float* __restrict__ Wk,
                         const float* __restrict__ Wv, const float* __restrict__ Wo,
                         const float* __restrict__ b1, const float* __restrict__ b2,
                         const float* __restrict__ bq, const float* __restrict__ bk,
                         const float* __restrict__ bv, const float* __restrict__ bo,
                         uint16_t* __restrict__ W1T, uint16_t* __restrict__ W2T,
                         uint16_t* __restrict__ WqkvT, uint16_t* __restrict__ WoT,
                         uint16_t* __restrict__ xb, uint16_t* __restrict__ bbase)
{
    const int id = blockIdx.x;
    const int tx = threadIdx.x, ty = threadIdx.y;
    const int tid = ty * 32 + tx;
    if (id < 2048) {
        __shared__ uint16_t t[32][33];
        const float* src; uint16_t* dst; int R, C, tile;
        if      (id < 512)  { src = W1; dst = W1T;              R = 512;  C = 1024; tile = id; }
        else if (id < 1024) { src = W2; dst = W2T;              R = 1024; C = 512;  tile = id - 512; }
        else if (id < 1280) { src = Wq; dst = WqkvT;            R = 512;  C = 512;  tile = id - 1024; }
        else if (id < 1536) { src = Wk; dst = WqkvT + 512*512;  R = 512;  C = 512;  tile = id - 1280; }
        else if (id < 1792) { src = Wv; dst = WqkvT + 1024*512; R = 512;  C = 512;  tile = id - 1536; }
        else                { src = Wo; dst = WoT;              R = 512;  C = 512;  tile = id - 1792; }
        const int ntx = C / 32;
        const int bx = (tile % ntx) * 32, by = (tile / ntx) * 32;
#pragma unroll
        for (int i = ty; i < 32; i += 8) t[i][tx] = f2bf(src[(size_t)(by + i) * C + bx + tx]);
        __syncthreads();
#pragma unroll
        for (int i = ty; i < 32; i += 8) dst[(size_t)(bx + i) * R + by + tx] = t[tx][i];
    } else if (id < 6144) {
        int i = (id - 2048) * 256 + tid;
        float4 v = ((const float4*)x)[i];
        ushort4 o;
        o.x = f2bf(v.x); o.y = f2bf(v.y); o.z = f2bf(v.z); o.w = f2bf(v.w);
        ((ushort4*)xb)[i] = o;
    } else {
        int i = (id - 6144) * 256 + tid;
        if      (i < 1024) bbase[i] = f2bf(b1[i]);
        else if (i < 1536) bbase[i] = f2bf(b2[i - 1024]);
        else if (i < 2048) bbase[i] = f2bf(bq[i - 1536]);
        else if (i < 2560) bbase[i] = f2bf(bk[i - 2048]);
        else if (i < 3072) bbase[i] = f2bf(bv[i - 2560]);
        else if (i < 3584) bbase[i] = f2bf(bo[i - 3072]);
    }
}

// ---------------------------------------------------------------------------
// Pipelined GEMM 64x128, BK=64, XOR-swizzled, double-buffered, vmcnt(6).
// XCD-swizzled block mapping (A fetched once chip-wide).
// ---------------------------------------------------------------------------
template<int RELU, int F32OUT>
__global__ __launch_bounds__(256, 3)
void gemm_k64(const uint16_t* __restrict__ A, const uint16_t* __restrict__ Bt,
              const uint16_t* __restrict__ bias, void* __restrict__ Cv,
              int M, int N, int K)
{
    __shared__ __align__(16) uint16_t lsA[2][64 * 64];
    __shared__ __align__(16) uint16_t lsB[2][128 * 64];

    const int tid = threadIdx.x, lane = tid & 63;
    const int wid = tid >> 6;
    const int quad = lane >> 4, lm = lane & 15;
    const int wm = wid >> 1, wn = wid & 1;
    const int2 sw = xcd_swz();
    const int m0 = sw.x * 64, n0 = sw.y * 128;

    f32x4 acc[2][4];
#pragma unroll
    for (int i = 0; i < 2; ++i)
#pragma unroll
        for (int j = 0; j < 4; ++j) acc[i][j] = (f32x4){0.f, 0.f, 0.f, 0.f};

    auto stage = [&](int k0, int bb) {
#pragma unroll
        for (int c4 = 0; c4 < 2; ++c4) {          // A: 512 chunks
            const int chunk = c4 * 256 + tid;
            const int r = chunk >> 3, lc = (chunk & 7) ^ (r & 7);
            gld_lds16(A + (size_t)(m0 + r) * K + k0 + lc * 8, &lsA[bb][(size_t)chunk * 8]);
        }
#pragma unroll
        for (int c4 = 0; c4 < 4; ++c4) {          // B: 1024 chunks
            const int chunk = c4 * 256 + tid;
            const int r = chunk >> 3, lc = (chunk & 7) ^ (r & 7);
            gld_lds16(Bt + (size_t)(n0 + r) * K + k0 + lc * 8, &lsB[bb][(size_t)chunk * 8]);
        }
    };
    auto compute = [&](int bb) {
#pragma unroll
        for (int kh = 0; kh < 2; ++kh) {
            const int pc = ((kh * 4 + quad) ^ (lm & 7));
            bf16x8 af[2], bfr[4];
#pragma unroll
            for (int t = 0; t < 2; ++t)
                af[t] = *(const bf16x8*)(&lsA[bb][(wm * 32 + t * 16 + lm) * 64 + pc * 8]);
#pragma unroll
            for (int t = 0; t < 4; ++t)
                bfr[t] = *(const bf16x8*)(&lsB[bb][(wn * 64 + t * 16 + lm) * 64 + pc * 8]);
#pragma unroll
            for (int i = 0; i < 2; ++i)
#pragma unroll
                for (int j = 0; j < 4; ++j)
                    acc[i][j] = __builtin_amdgcn_mfma_f32_16x16x32_bf16(af[i], bfr[j], acc[i][j], 0, 0, 0);
        }
    };

    stage(0, 0);
    int cur = 0;
#pragma unroll 1
    for (int k0 = 64; k0 < K; k0 += 64) {
        stage(k0, cur ^ 1);
        asm volatile("s_waitcnt vmcnt(6)" ::: "memory");
        __builtin_amdgcn_sched_barrier(0);
        __builtin_amdgcn_s_barrier();
        compute(cur);
        __builtin_amdgcn_s_barrier();
        cur ^= 1;
    }
    asm volatile("s_waitcnt vmcnt(0)" ::: "memory");
    __builtin_amdgcn_sched_barrier(0);
    __builtin_amdgcn_s_barrier();
    compute(cur);

#pragma unroll
    for (int i = 0; i < 2; ++i) {
        const int r0 = m0 + wm * 32 + i * 16 + quad * 4;
#pragma unroll
        for (int j = 0; j < 4; ++j) {
            const int col = n0 + wn * 64 + j * 16 + lm;
            const float bvj = bf2f(bias[col]);
#pragma unroll
            for (int r = 0; r < 4; ++r) {
                float v = acc[i][j][r] + bvj;
                if (RELU) v = fmaxf(v, 0.f);
                if (F32OUT) ((float*)Cv)[(size_t)(r0 + r) * N + col] = v;
                else        ((uint16_t*)Cv)[(size_t)(r0 + r) * N + col] = f2bf(v);
            }
        }
    }
}

// ---------------------------------------------------------------------------
// Pipelined GEMM 32x128, BK=64, XOR-swizzled, double-buffered, vmcnt(5).
// XCD-swizzled block mapping.
// ---------------------------------------------------------------------------
template<int RELU, int F32OUT>
__global__ __launch_bounds__(256, 4)
void gemm_k32(const uint16_t* __restrict__ A, const uint16_t* __restrict__ Bt,
              const uint16_t* __restrict__ bias, void* __restrict__ Cv,
              int M, int N, int K)
{
    __shared__ __align__(16) uint16_t lsA[2][32 * 64];
    __shared__ __align__(16) uint16_t lsB[2][128 * 64];

    const int tid = threadIdx.x, lane = tid & 63;
    const int wid = tid >> 6;
    const int quad = lane >> 4, lm = lane & 15;
    const int wm = wid >> 1, wn = wid & 1;
    const int2 sw = xcd_swz();
    const int m0 = sw.x * 32, n0 = sw.y * 128;

    f32x4 acc[4];
#pragma unroll
    for (int j = 0; j < 4; ++j) acc[j] = (f32x4){0.f, 0.f, 0.f, 0.f};

    auto stage = [&](int k0, int bb) {
        {                                          // A: 256 chunks (1/thread)
            const int chunk = tid;
            const int r = chunk >> 3, lc = (chunk & 7) ^ (r & 7);
            gld_lds16(A + (size_t)(m0 + r) * K + k0 + lc * 8, &lsA[bb][(size_t)chunk * 8]);
        }
#pragma unroll
        for (int c4 = 0; c4 < 4; ++c4) {          // B: 1024 chunks
            const int chunk = c4 * 256 + tid;
            const int r = chunk >> 3, lc = (chunk & 7) ^ (r & 7);
            gld_lds16(Bt + (size_t)(n0 + r) * K + k0 + lc * 8, &lsB[bb][(size_t)chunk * 8]);
        }
    };
    auto compute = [&](int bb) {
#pragma unroll
        for (int kh = 0; kh < 2; ++kh) {
            const int pc = ((kh * 4 + quad) ^ (lm & 7));
            bf16x8 af = *(const bf16x8*)(&lsA[bb][(wm * 16 + lm) * 64 + pc * 8]);
            bf16x8 bfr[4];
#pragma unroll
            for (int t = 0; t < 4; ++t)
                bfr[t] = *(const bf16x8*)(&lsB[bb][(wn * 64 + t * 16 + lm) * 64 + pc * 8]);
#pragma unroll
            for (int j = 0; j < 4; ++j)
                acc[j] = __builtin_amdgcn_mfma_f32_16x16x32_bf16(af, bfr[j], acc[j], 0, 0, 0);
        }
    };

    stage(0, 0);
    int cur = 0;
#pragma unroll 1
    for (int k0 = 64; k0 < K; k0 += 64) {
        stage(k0, cur ^ 1);
        asm volatile("s_waitcnt vmcnt(5)" ::: "memory");
        __builtin_amdgcn_sched_barrier(0);
        __builtin_amdgcn_s_barrier();
        compute(cur);
        __builtin_amdgcn_s_barrier();
        cur ^= 1;
    }
    asm volatile("s_waitcnt vmcnt(0)" ::: "memory");
    __builtin_amdgcn_sched_barrier(0);
    __builtin_amdgcn_s_barrier();
    compute(cur);

    const int r0 = m0 + wm * 16 + quad * 4;
#pragma unroll
    for (int j = 0; j < 4; ++j) {
        const int col = n0 + wn * 64 + j * 16 + lm;
        const float bvj = bf2f(bias[col]);
#pragma unroll
        for (int r = 0; r < 4; ++r) {
            float v = acc[j][r] + bvj;
            if (RELU) v = fmaxf(v, 0.f);
            if (F32OUT) ((float*)Cv)[(size_t)(r0 + r) * N + col] = v;
            else        ((uint16_t*)Cv)[(size_t)(r0 + r) * N + col] = f2bf(v);
        }
    }
}

// ---------------------------------------------------------------------------
// QKV GEMM (K=512, 64x128 tiles, dbuf, vmcnt(6), XCD-swizzled):
// Q,K -> qk[8192][1024]; V -> Vt transposed, key-permuted
// (pos(k)=(k&32)|((k&12)<<1)|(((k>>4)&1)<<2)|(k&3)), written COALESCED via
// LDS tile (col xor-swizzle).
// ---------------------------------------------------------------------------
__global__ __launch_bounds__(256, 3)
void gemm_qkv64(const uint16_t* __restrict__ A, const uint16_t* __restrict__ Bt,
                const uint16_t* __restrict__ bq, const uint16_t* __restrict__ bk,
                const uint16_t* __restrict__ bv_,
                uint16_t* __restrict__ qk, uint16_t* __restrict__ Vt)
{
    __shared__ __align__(16) uint16_t lsA[2][64 * 64];
    __shared__ __align__(16) uint16_t lsB[2][128 * 64];

    const int tid = threadIdx.x, lane = tid & 63;
    const int wid = tid >> 6;
    const int quad = lane >> 4, lm = lane & 15;
    const int wm = wid >> 1, wn = wid & 1;
    const int2 sw = xcd_swz();
    const int m0 = sw.x * 64, n0 = sw.y * 128;
    const int part = n0 >> 9;
    const uint16_t* B = (part == 0) ? bq : (part == 1) ? bk : bv_;
    const int K = 512;

    f32x4 acc[2][4];
#pragma unroll
    for (int i = 0; i < 2; ++i)
#pragma unroll
        for (int j = 0; j < 4; ++j) acc[i][j] = (f32x4){0.f, 0.f, 0.f, 0.f};

    auto stage = [&](int k0, int bb) {
#pragma unroll
        for (int c4 = 0; c4 < 2; ++c4) {          // A: 512 chunks
            const int chunk = c4 * 256 + tid;
            const int r = chunk >> 3, lc = (chunk & 7) ^ (r & 7);
            gld_lds16(A + (size_t)(m0 + r) * K + k0 + lc * 8, &lsA[bb][(size_t)chunk * 8]);
        }
#pragma unroll
        for (int c4 = 0; c4 < 4; ++c4) {          // B: 1024 chunks
            const int chunk = c4 * 256 + tid;
            const int r = chunk >> 3, lc = (chunk & 7) ^ (r & 7);
            gld_lds16(Bt + (size_t)(n0 + r) * K + k0 + lc * 8, &lsB[bb][(size_t)chunk * 8]);
        }
    };
    auto compute = [&](int bb) {
#pragma unroll
        for (int kh = 0; kh < 2; ++kh) {
            const int pc = ((kh * 4 + quad) ^ (lm & 7));
            bf16x8 af[2], bfr[4];
#pragma unroll
            for (int t = 0; t < 2; ++t)
                af[t] = *(const bf16x8*)(&lsA[bb][(wm * 32 + t * 16 + lm) * 64 + pc * 8]);
#pragma unroll
            for (int t = 0; t < 4; ++t)
                bfr[t] = *(const bf16x8*)(&lsB[bb][(wn * 64 + t * 16 + lm) * 64 + pc * 8]);
#pragma unroll
            for (int i = 0; i < 2; ++i)
#pragma unroll
                for (int j = 0; j < 4; ++j)
                    acc[i][j] = __builtin_amdgcn_mfma_f32_16x16x32_bf16(af[i], bfr[j], acc[i][j], 0, 0, 0);
        }
    };

    stage(0, 0);
    int cur = 0;
#pragma unroll 1
    for (int k0 = 64; k0 < K; k0 += 64) {
        stage(k0, cur ^ 1);
        asm volatile("s_waitcnt vmcnt(6)" ::: "memory");
        __builtin_amdgcn_sched_barrier(0);
        __builtin_amdgcn_s_barrier();
        compute(cur);
        __builtin_amdgcn_s_barrier();
        cur ^= 1;
    }
    asm volatile("s_waitcnt vmcnt(0)" ::: "memory");
    __builtin_amdgcn_sched_barrier(0);
    __builtin_amdgcn_s_barrier();
    compute(cur);

    if (part < 2) {
#pragma unroll
        for (int i = 0; i < 2; ++i) {
            const int mb = m0 + wm * 32 + i * 16 + quad * 4;
#pragma unroll
            for (int j = 0; j < 4; ++j) {
                const int nl = (n0 & 511) + wn * 64 + j * 16 + lm;
                const float bvj = bf2f(B[nl]);
#pragma unroll
                for (int r = 0; r < 4; ++r)
                    qk[(size_t)(mb + r) * 1024 + part * 512 + nl] = f2bf(acc[i][j][r] + bvj);
            }
        }
    } else {
        // V: stage [128 hd][64 key(permuted)] into LDS (cols ^ (hd&7)<<3)
        __syncthreads();
        uint16_t* tb = &lsB[0][0];                 // 16 KiB scratch
#pragma unroll
        for (int i = 0; i < 2; ++i) {
#pragma unroll
            for (int j = 0; j < 4; ++j) {
                const int hd = wn * 64 + j * 16 + lm;
                const float bvj = bf2f(B[(n0 & 511) + hd]);
#pragma unroll
                for (int r = 0; r < 4; ++r) {
                    const int kk = wm * 32 + i * 16 + quad * 4 + r;
                    const int kp = (kk & 32) | ((kk & 12) << 1) | (((kk >> 4) & 1) << 2) | (kk & 3);
                    tb[hd * 64 + (kp ^ ((hd & 7) << 3))] = f2bf(acc[i][j][r] + bvj);
                }
            }
        }
        __syncthreads();
        const int b = m0 >> 11, s0 = m0 & 2047, h0 = (n0 & 511) >> 6;
#pragma unroll
        for (int t2 = 0; t2 < 4; ++t2) {
            const int task = t2 * 256 + tid;
            const int hd = task >> 3, seg = task & 7;
            const bf16x8 v = *(const bf16x8*)(tb + hd * 64 + ((seg ^ (hd & 7)) << 3));
            const int hh = h0 + (hd >> 6), d = hd & 63;
            *(bf16x8*)(Vt + ((size_t)((b << 3) | hh) * 64 + d) * 2048 + s0 + seg * 8) = v;
        }
    }
}

// ---------------------------------------------------------------------------
// Flash attention, inverse band mask (|i-j|<=5 excluded). Fixed-scale softmax.
// SWAPPED QK^T (S^T in regs), in-register P via pre-permuted Vt key order.
// 8 waves, KEY-SPLIT (qw=wid&3 owns 32 q-rows; kh2=wid>>2 owns 64-key half).
// v5: NO LDS STAGING — K/V are L2-resident (XCD swizzle: FETCH 70->13MB
// measured), so K/V fragments are read DIRECTLY from global. No barriers in
// the main loop (waves run free; setprio arbitrates); LDS = 36KB reduction
// scratch only. XOR-swizzles cancel: logical K col = ks*4+quad, V col =
// gs*4+quad (derived from the staged version's stage/read address algebra).
// ---------------------------------------------------------------------------
__global__ __launch_bounds__(512, 4)
void attn_k(const uint16_t* __restrict__ qk, const uint16_t* __restrict__ Vt,
            uint16_t* __restrict__ Out)
{
    __shared__ __align__(16) f32x4 red[2304];          // 36,864 B reduction scratch

    const int tid = threadIdx.x, lane = tid & 63, wid = tid >> 6;
    const int qw = wid & 3, kh2 = wid >> 2;
    const int quad = lane >> 4, lm = lane & 15;
    const int ib = blockIdx.y * 16 + blockIdx.x;
    const int xcd = ib & 7, kq = ib >> 3;
    const int bh = xcd * 4 + (kq >> 4), q0 = (kq & 15) * 128;
    const int b = bh >> 3, h = bh & 7;
    const float cscale = 0.125f * 1.44269504088896f;   // (1/sqrt(64))*log2(e)

    bf16x8 qf[2][2];
#pragma unroll
    for (int i = 0; i < 2; ++i)
#pragma unroll
        for (int ks = 0; ks < 2; ++ks) {
            bf16x8 q = *(const bf16x8*)(qk +
                (size_t)(b * 2048 + q0 + qw * 32 + i * 16 + lm) * 1024 + h * 64 + ks * 32 + quad * 8);
#pragma unroll
            for (int e = 0; e < 8; ++e)
                q[e] = (short)f2bf(bf2f((uint16_t)q[e]) * cscale);
            qf[i][ks] = q;
        }

    f32x4 oacc[2][4];
#pragma unroll
    for (int i = 0; i < 2; ++i)
#pragma unroll
        for (int n = 0; n < 4; ++n) oacc[i][n] = (f32x4){0.f, 0.f, 0.f, 0.f};
    float lrow[2] = {0.f, 0.f};

    // per-wave K row base (row = j0 + kh2*64 + j*16 + lm), col = (ks*4+quad)*8
    const uint16_t* Kb = qk + (size_t)(b * 2048 + kh2 * 64 + lm) * 1024 + 512 + h * 64 + quad * 8;
    // per-wave V row base (row d = n*16+lm), col = j0 + (gs*4+quad)*8
    const uint16_t* Vb = Vt + (size_t)(bh * 64 + lm) * 2048 + quad * 8;

#pragma unroll 1
    for (int jt = 0; jt < 16; ++jt) {
        const int j0 = jt * 128;

        // S^T = K Q^T, K direct from L2
        f32x4 sacc[2][4];
#pragma unroll
        for (int i = 0; i < 2; ++i)
#pragma unroll
            for (int j = 0; j < 4; ++j) sacc[i][j] = (f32x4){0.f, 0.f, 0.f, 0.f};
        __builtin_amdgcn_s_setprio(1);
#pragma unroll
        for (int ks = 0; ks < 2; ++ks)
#pragma unroll
            for (int j = 0; j < 4; ++j) {
                bf16x8 kf = *(const bf16x8*)(Kb + (size_t)(j0 + j * 16) * 1024 + ks * 32);
#pragma unroll
                for (int i = 0; i < 2; ++i)
                    sacc[i][j] = __builtin_amdgcn_mfma_f32_16x16x32_bf16(kf, qf[i][ks], sacc[i][j], 0, 0, 0);
            }
        __builtin_amdgcn_s_setprio(0);

        // band mask (uniform branch); q depends on lm, key on quad*4+r
        if ((j0 + 127 >= q0 - 5) && (j0 <= q0 + 127 + 5)) {
#pragma unroll
            for (int i = 0; i < 2; ++i) {
                const int qr = q0 + qw * 32 + i * 16 + lm;
#pragma unroll
                for (int j = 0; j < 4; ++j)
#pragma unroll
                    for (int r = 0; r < 4; ++r) {
                        int kc = j0 + kh2 * 64 + j * 16 + quad * 4 + r;
                        int dd = qr - kc; if (dd < 0) dd = -dd;
                        if (dd <= 5) sacc[i][j][r] = -1e30f;
                    }
            }
        }

        // p = exp2(s); pack in-register -> PV A-fragment; O += P V (V direct)
#pragma unroll
        for (int ksl = 0; ksl < 2; ++ksl) {
            const int gs = kh2 * 2 + ksl;
            bf16x8 pa[2];
#pragma unroll
            for (int i = 0; i < 2; ++i) {
                const float p0 = fexp2(sacc[i][2 * ksl + 0][0]);
                const float p1 = fexp2(sacc[i][2 * ksl + 0][1]);
                const float p2 = fexp2(sacc[i][2 * ksl + 0][2]);
                const float p3 = fexp2(sacc[i][2 * ksl + 0][3]);
                const float p4 = fexp2(sacc[i][2 * ksl + 1][0]);
                const float p5 = fexp2(sacc[i][2 * ksl + 1][1]);
                const float p6 = fexp2(sacc[i][2 * ksl + 1][2]);
                const float p7 = fexp2(sacc[i][2 * ksl + 1][3]);
                lrow[i] += ((p0 + p1) + (p2 + p3)) + ((p4 + p5) + (p6 + p7));
                union { bf16x8 v; uint32_t u[4]; } c;
                c.u[0] = pk2bf(p0, p1);
                c.u[1] = pk2bf(p2, p3);
                c.u[2] = pk2bf(p4, p5);
                c.u[3] = pk2bf(p6, p7);
                pa[i] = c.v;
            }
            __builtin_amdgcn_s_setprio(1);
#pragma unroll
            for (int n = 0; n < 4; ++n) {
                bf16x8 vf = *(const bf16x8*)(Vb + (size_t)(n * 16) * 2048 + j0 + gs * 32);
#pragma unroll
                for (int i = 0; i < 2; ++i)
                    oacc[i][n] = __builtin_amdgcn_mfma_f32_16x16x32_bf16(pa[i], vf, oacc[i][n], 0, 0, 0);
            }
            __builtin_amdgcn_s_setprio(0);
        }
    }

    // combine key-half partials via LDS
    __syncthreads();
    if (wid >= 4) {
        const int base = ((wid - 4) * 64 + lane) * 9;
#pragma unroll
        for (int i = 0; i < 2; ++i)
#pragma unroll
            for (int n = 0; n < 4; ++n) red[base + i * 4 + n] = oacc[i][n];
        red[base + 8] = (f32x4){lrow[0], lrow[1], 0.f, 0.f};
    }
    __syncthreads();
    if (wid < 4) {
        const int base = (wid * 64 + lane) * 9;
#pragma unroll
        for (int i = 0; i < 2; ++i)
#pragma unroll
            for (int n = 0; n < 4; ++n) oacc[i][n] += red[base + i * 4 + n];
        const f32x4 lr = red[base + 8];
        lrow[0] += lr[0]; lrow[1] += lr[1];

#pragma unroll
        for (int i = 0; i < 2; ++i) {
            float l = lrow[i];
            l += __shfl_xor(l, 16);
            l += __shfl_xor(l, 32);
            const float inv = 1.f / (l + 1e-30f);
#pragma unroll
            for (int r = 0; r < 4; ++r) {
                const float invr = __shfl(inv, quad * 4 + r, 16);
                const int s = q0 + wid * 32 + i * 16 + quad * 4 + r;
#pragma unroll
                for (int n = 0; n < 4; ++n)
                    Out[(size_t)(b * 2048 + s) * 512 + h * 64 + n * 16 + lm] = f2bf(oacc[i][n][r] * invr);
            }
        }
    }
}

// ---------------------------------------------------------------------------
// Launch — fp32 in, fp32 out; ws peak 37 MiB; 6 dispatches.
// ---------------------------------------------------------------------------
extern "C" void kernel_launch(void* const* d_in, const int* in_sizes, int n_in,
                              void* d_out, int out_size, void* d_ws, size_t ws_size,
                              hipStream_t stream)
{
    const float* x  = (const float*)d_in[0];
    const float* W1 = (const float*)d_in[1];
    const float* b1 = (const float*)d_in[2];
    const float* W2 = (const float*)d_in[3];
    const float* b2 = (const float*)d_in[4];
    const float* Wq = (const float*)d_in[5];
    const float* bq = (const float*)d_in[6];
    const float* Wk = (const float*)d_in[7];
    const float* bk = (const float*)d_in[8];
    const float* Wv = (const float*)d_in[9];
    const float* bv = (const float*)d_in[10];
    const float* Wo = (const float*)d_in[11];
    const float* bo = (const float*)d_in[12];
    (void)in_sizes; (void)n_in; (void)out_size; (void)ws_size;

    char* ws = (char*)d_ws;
    const size_t MiB = 1024 * 1024;
    uint16_t* xb    = (uint16_t*)(ws + 0);                       // 8 MiB [dead after G1]
    uint16_t* W1T   = (uint16_t*)(ws + 8 * MiB);                 // 1 MiB  [1024][512]
    uint16_t* W2T   = (uint16_t*)(ws + 9 * MiB);                 // 1 MiB  [512][1024]
    uint16_t* WqkvT = (uint16_t*)(ws + 10 * MiB);                // 1.5 MiB [1536][512]
    uint16_t* WoT   = (uint16_t*)(ws + 11 * MiB + 512 * 1024);   // 0.5 MiB [512][512]
    uint16_t* bbase = (uint16_t*)(ws + 12 * MiB);                // 3584 u16
    uint16_t* b1b = bbase, *b2b = bbase + 1024, *bqb = bbase + 1536;
    uint16_t* bkb = bbase + 2048, *bvb = bbase + 2560, *bob = bbase + 3072;
    uint16_t* xm1   = (uint16_t*)(ws + 13 * MiB);                // 16 MiB [13,29)
    uint16_t* xm    = (uint16_t*)(ws + 29 * MiB);                //  8 MiB [29,37)
    uint16_t* qk    = xm1;   // aliases xm1 (dead after G2)
    uint16_t* att   = xm;    // aliases xm  (dead after QKV gemm)
    uint16_t* Vt    = xb;    // aliases xb  (dead after G1)

    prep_all<<<6158, dim3(32, 8), 0, stream>>>(x, W1, W2, Wq, Wk, Wv, Wo,
                                               b1, b2, bq, bk, bv, bo,
                                               W1T, W2T, WqkvT, WoT, xb, bbase);

    gemm_k64<1,0><<<dim3(8, 128),  256, 0, stream>>>(xb,  W1T, b1b, xm1, 8192, 1024, 512);
    gemm_k32<0,0><<<dim3(4, 256),  256, 0, stream>>>(xm1, W2T, b2b, xm,  8192, 512, 1024);
    gemm_qkv64   <<<dim3(12, 128), 256, 0, stream>>>(xm, WqkvT, bqb, bkb, bvb, qk, Vt);
    attn_k       <<<dim3(16, 32),  512, 0, stream>>>(qk, Vt, att);
    gemm_k32<0,1><<<dim3(4, 256),  256, 0, stream>>>(att, WoT, bob, d_out, 8192, 512, 512);
}

// Round 13
// 201.083 us; speedup vs baseline: 1.3503x; 1.3503x over previous
//
#include <hip/hip_runtime.h>
#include <stdint.h>

typedef __attribute__((ext_vector_type(8))) short bf16x8;
typedef __attribute__((ext_vector_type(4))) float f32x4;

__device__ __forceinline__ float bf2f(uint16_t u) {
    union { uint32_t u; float f; } c; c.u = ((uint32_t)u) << 16; return c.f;
}
__device__ __forceinline__ uint16_t f2bf(float f) {
    union { float f; uint32_t u; } c; c.f = f;
    uint32_t r = c.u + 0x7fffu + ((c.u >> 16) & 1u);
    return (uint16_t)(r >> 16);
}
__device__ __forceinline__ uint32_t pk2bf(float a, float b) {
#if __has_builtin(__builtin_amdgcn_cvt_pk_bf16_f32)
    auto v = __builtin_amdgcn_cvt_pk_bf16_f32(a, b);
    uint32_t u; __builtin_memcpy(&u, &v, 4); return u;
#else
    return (uint32_t)f2bf(a) | ((uint32_t)f2bf(b) << 16);
#endif
}
// raw v_exp_f32 (no OCML wrapper); exp2(-huge) -> 0 correctly
__device__ __forceinline__ float fexp2(float x) {
#if __has_builtin(__builtin_amdgcn_exp2f)
    return __builtin_amdgcn_exp2f(x);
#else
    return exp2f(x);
#endif
}

// async global->LDS, 16B/lane; LDS dest must be wave-uniform base + lane*16.
__device__ __forceinline__ void gld_lds16(const uint16_t* g, uint16_t* l) {
    __builtin_amdgcn_global_load_lds(
        (const __attribute__((address_space(1))) void*)g,
        (__attribute__((address_space(3))) void*)l, 16, 0, 0);
}

// Bijective XCD swizzle (T1): XCD c owns a contiguous M-range x all N-tiles,
// so the A panel is fetched once chip-wide and N-sharing blocks co-reside in
// one L2. Requires gridDim.y % 8 == 0. Returns (mtile, ntile).
// Measured: total 211.6 -> 206.2us when applied to all 4 GEMMs (R11).
__device__ __forceinline__ int2 xcd_swz() {
    const int nx = gridDim.x;
    const int ib = blockIdx.y * nx + blockIdx.x;
    const int c = ib & 7, j = ib >> 3;
    const int mpx = gridDim.y >> 3;
    return make_int2(c * mpx + j / nx, j % nx);
}

// ---------------------------------------------------------------------------
// Single fused prep (weights transpose, x convert, bias convert)
// ---------------------------------------------------------------------------
__global__ void prep_all(const float* __restrict__ x,
                         const float* __restrict__ W1, const float* __restrict__ W2,
                         const float* __restrict__ Wq, const float* __restrict__ Wk,
                         const float* __restrict__ Wv, const float* __restrict__ Wo,
                         const float* __restrict__ b1, const float* __restrict__ b2,
                         const float* __restrict__ bq, const float* __restrict__ bk,
                         const float* __restrict__ bv, const float* __restrict__ bo,
                         uint16_t* __restrict__ W1T, uint16_t* __restrict__ W2T,
                         uint16_t* __restrict__ WqkvT, uint16_t* __restrict__ WoT,
                         uint16_t* __restrict__ xb, uint16_t* __restrict__ bbase)
{
    const int id = blockIdx.x;
    const int tx = threadIdx.x, ty = threadIdx.y;
    const int tid = ty * 32 + tx;
    if (id < 2048) {
        __shared__ uint16_t t[32][33];
        const float* src; uint16_t* dst; int R, C, tile;
        if      (id < 512)  { src = W1; dst = W1T;              R = 512;  C = 1024; tile = id; }
        else if (id < 1024) { src = W2; dst = W2T;              R = 1024; C = 512;  tile = id - 512; }
        else if (id < 1280) { src = Wq; dst = WqkvT;            R = 512;  C = 512;  tile = id - 1024; }
        else if (id < 1536) { src = Wk; dst = WqkvT + 512*512;  R = 512;  C = 512;  tile = id - 1280; }
        else if (id < 1792) { src = Wv; dst = WqkvT + 1024*512; R = 512;  C = 512;  tile = id - 1536; }
        else                { src = Wo; dst = WoT;              R = 512;  C = 512;  tile = id - 1792; }
        const int ntx = C / 32;
        const int bx = (tile % ntx) * 32, by = (tile / ntx) * 32;
#pragma unroll
        for (int i = ty; i < 32; i += 8) t[i][tx] = f2bf(src[(size_t)(by + i) * C + bx + tx]);
        __syncthreads();
#pragma unroll
        for (int i = ty; i < 32; i += 8) dst[(size_t)(bx + i) * R + by + tx] = t[tx][i];
    } else if (id < 6144) {
        int i = (id - 2048) * 256 + tid;
        float4 v = ((const float4*)x)[i];
        ushort4 o;
        o.x = f2bf(v.x); o.y = f2bf(v.y); o.z = f2bf(v.z); o.w = f2bf(v.w);
        ((ushort4*)xb)[i] = o;
    } else {
        int i = (id - 6144) * 256 + tid;
        if      (i < 1024) bbase[i] = f2bf(b1[i]);
        else if (i < 1536) bbase[i] = f2bf(b2[i - 1024]);
        else if (i < 2048) bbase[i] = f2bf(bq[i - 1536]);
        else if (i < 2560) bbase[i] = f2bf(bk[i - 2048]);
        else if (i < 3072) bbase[i] = f2bf(bv[i - 2560]);
        else if (i < 3584) bbase[i] = f2bf(bo[i - 3072]);
    }
}

// ---------------------------------------------------------------------------
// Pipelined GEMM 64x128, BK=64, XOR-swizzled, double-buffered, vmcnt(6).
// XCD-swizzled block mapping (A fetched once chip-wide).
// ---------------------------------------------------------------------------
template<int RELU, int F32OUT>
__global__ __launch_bounds__(256, 3)
void gemm_k64(const uint16_t* __restrict__ A, const uint16_t* __restrict__ Bt,
              const uint16_t* __restrict__ bias, void* __restrict__ Cv,
              int M, int N, int K)
{
    __shared__ __align__(16) uint16_t lsA[2][64 * 64];
    __shared__ __align__(16) uint16_t lsB[2][128 * 64];

    const int tid = threadIdx.x, lane = tid & 63;
    const int wid = tid >> 6;
    const int quad = lane >> 4, lm = lane & 15;
    const int wm = wid >> 1, wn = wid & 1;
    const int2 sw = xcd_swz();
    const int m0 = sw.x * 64, n0 = sw.y * 128;

    f32x4 acc[2][4];
#pragma unroll
    for (int i = 0; i < 2; ++i)
#pragma unroll
        for (int j = 0; j < 4; ++j) acc[i][j] = (f32x4){0.f, 0.f, 0.f, 0.f};

    auto stage = [&](int k0, int bb) {
#pragma unroll
        for (int c4 = 0; c4 < 2; ++c4) {          // A: 512 chunks
            const int chunk = c4 * 256 + tid;
            const int r = chunk >> 3, lc = (chunk & 7) ^ (r & 7);
            gld_lds16(A + (size_t)(m0 + r) * K + k0 + lc * 8, &lsA[bb][(size_t)chunk * 8]);
        }
#pragma unroll
        for (int c4 = 0; c4 < 4; ++c4) {          // B: 1024 chunks
            const int chunk = c4 * 256 + tid;
            const int r = chunk >> 3, lc = (chunk & 7) ^ (r & 7);
            gld_lds16(Bt + (size_t)(n0 + r) * K + k0 + lc * 8, &lsB[bb][(size_t)chunk * 8]);
        }
    };
    auto compute = [&](int bb) {
#pragma unroll
        for (int kh = 0; kh < 2; ++kh) {
            const int pc = ((kh * 4 + quad) ^ (lm & 7));
            bf16x8 af[2], bfr[4];
#pragma unroll
            for (int t = 0; t < 2; ++t)
                af[t] = *(const bf16x8*)(&lsA[bb][(wm * 32 + t * 16 + lm) * 64 + pc * 8]);
#pragma unroll
            for (int t = 0; t < 4; ++t)
                bfr[t] = *(const bf16x8*)(&lsB[bb][(wn * 64 + t * 16 + lm) * 64 + pc * 8]);
#pragma unroll
            for (int i = 0; i < 2; ++i)
#pragma unroll
                for (int j = 0; j < 4; ++j)
                    acc[i][j] = __builtin_amdgcn_mfma_f32_16x16x32_bf16(af[i], bfr[j], acc[i][j], 0, 0, 0);
        }
    };

    stage(0, 0);
    int cur = 0;
#pragma unroll 1
    for (int k0 = 64; k0 < K; k0 += 64) {
        stage(k0, cur ^ 1);
        asm volatile("s_waitcnt vmcnt(6)" ::: "memory");
        __builtin_amdgcn_sched_barrier(0);
        __builtin_amdgcn_s_barrier();
        compute(cur);
        __builtin_amdgcn_s_barrier();
        cur ^= 1;
    }
    asm volatile("s_waitcnt vmcnt(0)" ::: "memory");
    __builtin_amdgcn_sched_barrier(0);
    __builtin_amdgcn_s_barrier();
    compute(cur);

#pragma unroll
    for (int i = 0; i < 2; ++i) {
        const int r0 = m0 + wm * 32 + i * 16 + quad * 4;
#pragma unroll
        for (int j = 0; j < 4; ++j) {
            const int col = n0 + wn * 64 + j * 16 + lm;
            const float bvj = bf2f(bias[col]);
#pragma unroll
            for (int r = 0; r < 4; ++r) {
                float v = acc[i][j][r] + bvj;
                if (RELU) v = fmaxf(v, 0.f);
                if (F32OUT) ((float*)Cv)[(size_t)(r0 + r) * N + col] = v;
                else        ((uint16_t*)Cv)[(size_t)(r0 + r) * N + col] = f2bf(v);
            }
        }
    }
}

// ---------------------------------------------------------------------------
// Pipelined GEMM 32x128, BK=64, XOR-swizzled, double-buffered, vmcnt(5).
// XCD-swizzled block mapping.
// ---------------------------------------------------------------------------
template<int RELU, int F32OUT>
__global__ __launch_bounds__(256, 4)
void gemm_k32(const uint16_t* __restrict__ A, const uint16_t* __restrict__ Bt,
              const uint16_t* __restrict__ bias, void* __restrict__ Cv,
              int M, int N, int K)
{
    __shared__ __align__(16) uint16_t lsA[2][32 * 64];
    __shared__ __align__(16) uint16_t lsB[2][128 * 64];

    const int tid = threadIdx.x, lane = tid & 63;
    const int wid = tid >> 6;
    const int quad = lane >> 4, lm = lane & 15;
    const int wm = wid >> 1, wn = wid & 1;
    const int2 sw = xcd_swz();
    const int m0 = sw.x * 32, n0 = sw.y * 128;

    f32x4 acc[4];
#pragma unroll
    for (int j = 0; j < 4; ++j) acc[j] = (f32x4){0.f, 0.f, 0.f, 0.f};

    auto stage = [&](int k0, int bb) {
        {                                          // A: 256 chunks (1/thread)
            const int chunk = tid;
            const int r = chunk >> 3, lc = (chunk & 7) ^ (r & 7);
            gld_lds16(A + (size_t)(m0 + r) * K + k0 + lc * 8, &lsA[bb][(size_t)chunk * 8]);
        }
#pragma unroll
        for (int c4 = 0; c4 < 4; ++c4) {          // B: 1024 chunks
            const int chunk = c4 * 256 + tid;
            const int r = chunk >> 3, lc = (chunk & 7) ^ (r & 7);
            gld_lds16(Bt + (size_t)(n0 + r) * K + k0 + lc * 8, &lsB[bb][(size_t)chunk * 8]);
        }
    };
    auto compute = [&](int bb) {
#pragma unroll
        for (int kh = 0; kh < 2; ++kh) {
            const int pc = ((kh * 4 + quad) ^ (lm & 7));
            bf16x8 af = *(const bf16x8*)(&lsA[bb][(wm * 16 + lm) * 64 + pc * 8]);
            bf16x8 bfr[4];
#pragma unroll
            for (int t = 0; t < 4; ++t)
                bfr[t] = *(const bf16x8*)(&lsB[bb][(wn * 64 + t * 16 + lm) * 64 + pc * 8]);
#pragma unroll
            for (int j = 0; j < 4; ++j)
                acc[j] = __builtin_amdgcn_mfma_f32_16x16x32_bf16(af, bfr[j], acc[j], 0, 0, 0);
        }
    };

    stage(0, 0);
    int cur = 0;
#pragma unroll 1
    for (int k0 = 64; k0 < K; k0 += 64) {
        stage(k0, cur ^ 1);
        asm volatile("s_waitcnt vmcnt(5)" ::: "memory");
        __builtin_amdgcn_sched_barrier(0);
        __builtin_amdgcn_s_barrier();
        compute(cur);
        __builtin_amdgcn_s_barrier();
        cur ^= 1;
    }
    asm volatile("s_waitcnt vmcnt(0)" ::: "memory");
    __builtin_amdgcn_sched_barrier(0);
    __builtin_amdgcn_s_barrier();
    compute(cur);

    const int r0 = m0 + wm * 16 + quad * 4;
#pragma unroll
    for (int j = 0; j < 4; ++j) {
        const int col = n0 + wn * 64 + j * 16 + lm;
        const float bvj = bf2f(bias[col]);
#pragma unroll
        for (int r = 0; r < 4; ++r) {
            float v = acc[j][r] + bvj;
            if (RELU) v = fmaxf(v, 0.f);
            if (F32OUT) ((float*)Cv)[(size_t)(r0 + r) * N + col] = v;
            else        ((uint16_t*)Cv)[(size_t)(r0 + r) * N + col] = f2bf(v);
        }
    }
}

// ---------------------------------------------------------------------------
// QKV GEMM (K=512, 64x128 tiles, dbuf, vmcnt(6), XCD-swizzled):
// Q,K -> qk[8192][1024]; V -> Vt transposed, key-permuted
// (pos(k)=(k&32)|((k&12)<<1)|(((k>>4)&1)<<2)|(k&3)), written COALESCED via
// LDS tile (col xor-swizzle).
// ---------------------------------------------------------------------------
__global__ __launch_bounds__(256, 3)
void gemm_qkv64(const uint16_t* __restrict__ A, const uint16_t* __restrict__ Bt,
                const uint16_t* __restrict__ bq, const uint16_t* __restrict__ bk,
                const uint16_t* __restrict__ bv_,
                uint16_t* __restrict__ qk, uint16_t* __restrict__ Vt)
{
    __shared__ __align__(16) uint16_t lsA[2][64 * 64];
    __shared__ __align__(16) uint16_t lsB[2][128 * 64];

    const int tid = threadIdx.x, lane = tid & 63;
    const int wid = tid >> 6;
    const int quad = lane >> 4, lm = lane & 15;
    const int wm = wid >> 1, wn = wid & 1;
    const int2 sw = xcd_swz();
    const int m0 = sw.x * 64, n0 = sw.y * 128;
    const int part = n0 >> 9;
    const uint16_t* B = (part == 0) ? bq : (part == 1) ? bk : bv_;
    const int K = 512;

    f32x4 acc[2][4];
#pragma unroll
    for (int i = 0; i < 2; ++i)
#pragma unroll
        for (int j = 0; j < 4; ++j) acc[i][j] = (f32x4){0.f, 0.f, 0.f, 0.f};

    auto stage = [&](int k0, int bb) {
#pragma unroll
        for (int c4 = 0; c4 < 2; ++c4) {          // A: 512 chunks
            const int chunk = c4 * 256 + tid;
            const int r = chunk >> 3, lc = (chunk & 7) ^ (r & 7);
            gld_lds16(A + (size_t)(m0 + r) * K + k0 + lc * 8, &lsA[bb][(size_t)chunk * 8]);
        }
#pragma unroll
        for (int c4 = 0; c4 < 4; ++c4) {          // B: 1024 chunks
            const int chunk = c4 * 256 + tid;
            const int r = chunk >> 3, lc = (chunk & 7) ^ (r & 7);
            gld_lds16(Bt + (size_t)(n0 + r) * K + k0 + lc * 8, &lsB[bb][(size_t)chunk * 8]);
        }
    };
    auto compute = [&](int bb) {
#pragma unroll
        for (int kh = 0; kh < 2; ++kh) {
            const int pc = ((kh * 4 + quad) ^ (lm & 7));
            bf16x8 af[2], bfr[4];
#pragma unroll
            for (int t = 0; t < 2; ++t)
                af[t] = *(const bf16x8*)(&lsA[bb][(wm * 32 + t * 16 + lm) * 64 + pc * 8]);
#pragma unroll
            for (int t = 0; t < 4; ++t)
                bfr[t] = *(const bf16x8*)(&lsB[bb][(wn * 64 + t * 16 + lm) * 64 + pc * 8]);
#pragma unroll
            for (int i = 0; i < 2; ++i)
#pragma unroll
                for (int j = 0; j < 4; ++j)
                    acc[i][j] = __builtin_amdgcn_mfma_f32_16x16x32_bf16(af[i], bfr[j], acc[i][j], 0, 0, 0);
        }
    };

    stage(0, 0);
    int cur = 0;
#pragma unroll 1
    for (int k0 = 64; k0 < K; k0 += 64) {
        stage(k0, cur ^ 1);
        asm volatile("s_waitcnt vmcnt(6)" ::: "memory");
        __builtin_amdgcn_sched_barrier(0);
        __builtin_amdgcn_s_barrier();
        compute(cur);
        __builtin_amdgcn_s_barrier();
        cur ^= 1;
    }
    asm volatile("s_waitcnt vmcnt(0)" ::: "memory");
    __builtin_amdgcn_sched_barrier(0);
    __builtin_amdgcn_s_barrier();
    compute(cur);

    if (part < 2) {
#pragma unroll
        for (int i = 0; i < 2; ++i) {
            const int mb = m0 + wm * 32 + i * 16 + quad * 4;
#pragma unroll
            for (int j = 0; j < 4; ++j) {
                const int nl = (n0 & 511) + wn * 64 + j * 16 + lm;
                const float bvj = bf2f(B[nl]);
#pragma unroll
                for (int r = 0; r < 4; ++r)
                    qk[(size_t)(mb + r) * 1024 + part * 512 + nl] = f2bf(acc[i][j][r] + bvj);
            }
        }
    } else {
        // V: stage [128 hd][64 key(permuted)] into LDS (cols ^ (hd&7)<<3)
        __syncthreads();
        uint16_t* tb = &lsB[0][0];                 // 16 KiB scratch
#pragma unroll
        for (int i = 0; i < 2; ++i) {
#pragma unroll
            for (int j = 0; j < 4; ++j) {
                const int hd = wn * 64 + j * 16 + lm;
                const float bvj = bf2f(B[(n0 & 511) + hd]);
#pragma unroll
                for (int r = 0; r < 4; ++r) {
                    const int kk = wm * 32 + i * 16 + quad * 4 + r;
                    const int kp = (kk & 32) | ((kk & 12) << 1) | (((kk >> 4) & 1) << 2) | (kk & 3);
                    tb[hd * 64 + (kp ^ ((hd & 7) << 3))] = f2bf(acc[i][j][r] + bvj);
                }
            }
        }
        __syncthreads();
        const int b = m0 >> 11, s0 = m0 & 2047, h0 = (n0 & 511) >> 6;
#pragma unroll
        for (int t2 = 0; t2 < 4; ++t2) {
            const int task = t2 * 256 + tid;
            const int hd = task >> 3, seg = task & 7;
            const bf16x8 v = *(const bf16x8*)(tb + hd * 64 + ((seg ^ (hd & 7)) << 3));
            const int hh = h0 + (hd >> 6), d = hd & 63;
            *(bf16x8*)(Vt + ((size_t)((b << 3) | hh) * 64 + d) * 2048 + s0 + seg * 8) = v;
        }
    }
}

// ---------------------------------------------------------------------------
// Flash attention, inverse band mask (|i-j|<=5 excluded). Fixed-scale softmax.
// SWAPPED QK^T (S^T in regs), in-register P via pre-permuted Vt key order.
// 8 waves, KEY-SPLIT (qw=wid&3 owns 32 q-rows; kh2=wid>>2 owns 64-key half).
// Double-buffered LDS staging, counted vmcnt(4). XCD-swizzled: one bh-group's
// 16 q-blocks per XCD -> K/V L2-resident (FETCH 70->13MB, 54.0us measured).
// NOTE (R12): removing the LDS staging regressed 54->125us — the staging's
// function is COALESCING (direct K/V reads are 64-line-per-instr strided),
// not capacity. Keep it.
// ---------------------------------------------------------------------------
__global__ __launch_bounds__(512, 4)
void attn_k(const uint16_t* __restrict__ qk, const uint16_t* __restrict__ Vt,
            uint16_t* __restrict__ Out)
{
    // [2 buffers][ K:128x64 | V:64x128 ] u16 = 64 KiB total
    __shared__ __align__(16) uint16_t lsAll[2][16384];

    const int tid = threadIdx.x, lane = tid & 63, wid = tid >> 6;
    const int qw = wid & 3, kh2 = wid >> 2;
    const int quad = lane >> 4, lm = lane & 15;
    const int ib = blockIdx.y * 16 + blockIdx.x;
    const int xcd = ib & 7, kq = ib >> 3;
    const int bh = xcd * 4 + (kq >> 4), q0 = (kq & 15) * 128;
    const int b = bh >> 3, h = bh & 7;
    const float cscale = 0.125f * 1.44269504088896f;   // (1/sqrt(64))*log2(e)

    bf16x8 qf[2][2];
#pragma unroll
    for (int i = 0; i < 2; ++i)
#pragma unroll
        for (int ks = 0; ks < 2; ++ks) {
            bf16x8 q = *(const bf16x8*)(qk +
                (size_t)(b * 2048 + q0 + qw * 32 + i * 16 + lm) * 1024 + h * 64 + ks * 32 + quad * 8);
#pragma unroll
            for (int e = 0; e < 8; ++e)
                q[e] = (short)f2bf(bf2f((uint16_t)q[e]) * cscale);
            qf[i][ks] = q;
        }

    f32x4 oacc[2][4];
#pragma unroll
    for (int i = 0; i < 2; ++i)
#pragma unroll
        for (int n = 0; n < 4; ++n) oacc[i][n] = (f32x4){0.f, 0.f, 0.f, 0.f};
    float lrow[2] = {0.f, 0.f};

    auto stage = [&](int j0, int bb) {
        uint16_t* lsK = &lsAll[bb][0];
        uint16_t* lsV = &lsAll[bb][8192];
#pragma unroll
        for (int c2 = 0; c2 < 2; ++c2) {
            const int chunk = c2 * 512 + tid;
            const int r = chunk >> 3, lc = (chunk & 7) ^ (r & 7);
            gld_lds16(qk + (size_t)(b * 2048 + j0 + r) * 1024 + 512 + h * 64 + lc * 8,
                      lsK + (size_t)chunk * 8);
        }
#pragma unroll
        for (int c2 = 0; c2 < 2; ++c2) {
            const int chunk = c2 * 512 + tid;
            const int d = chunk >> 4, lc = (chunk & 15) ^ (d & 15);
            gld_lds16(Vt + (size_t)(bh * 64 + d) * 2048 + j0 + lc * 8,
                      lsV + (size_t)chunk * 8);
        }
    };

    auto compute = [&](int j0, int bb) {
        const uint16_t* Kb = &lsAll[bb][0];
        const uint16_t* Vb = &lsAll[bb][8192];

        f32x4 sacc[2][4];
#pragma unroll
        for (int i = 0; i < 2; ++i)
#pragma unroll
            for (int j = 0; j < 4; ++j) sacc[i][j] = (f32x4){0.f, 0.f, 0.f, 0.f};
        __builtin_amdgcn_s_setprio(1);
#pragma unroll
        for (int ks = 0; ks < 2; ++ks)
#pragma unroll
            for (int j = 0; j < 4; ++j) {
                const int pc = (ks * 4 + quad) ^ (lm & 7);
                bf16x8 kf = *(const bf16x8*)(Kb + (kh2 * 64 + j * 16 + lm) * 64 + pc * 8);
#pragma unroll
                for (int i = 0; i < 2; ++i)
                    sacc[i][j] = __builtin_amdgcn_mfma_f32_16x16x32_bf16(kf, qf[i][ks], sacc[i][j], 0, 0, 0);
            }
        __builtin_amdgcn_s_setprio(0);

        if ((j0 + 127 >= q0 - 5) && (j0 <= q0 + 127 + 5)) {
#pragma unroll
            for (int i = 0; i < 2; ++i) {
                const int qr = q0 + qw * 32 + i * 16 + lm;
#pragma unroll
                for (int j = 0; j < 4; ++j)
#pragma unroll
                    for (int r = 0; r < 4; ++r) {
                        int kc = j0 + kh2 * 64 + j * 16 + quad * 4 + r;
                        int dd = qr - kc; if (dd < 0) dd = -dd;
                        if (dd <= 5) sacc[i][j][r] = -1e30f;
                    }
            }
        }

#pragma unroll
        for (int ksl = 0; ksl < 2; ++ksl) {
            const int gs = kh2 * 2 + ksl;
            bf16x8 pa[2];
#pragma unroll
            for (int i = 0; i < 2; ++i) {
                const float p0 = fexp2(sacc[i][2 * ksl + 0][0]);
                const float p1 = fexp2(sacc[i][2 * ksl + 0][1]);
                const float p2 = fexp2(sacc[i][2 * ksl + 0][2]);
                const float p3 = fexp2(sacc[i][2 * ksl + 0][3]);
                const float p4 = fexp2(sacc[i][2 * ksl + 1][0]);
                const float p5 = fexp2(sacc[i][2 * ksl + 1][1]);
                const float p6 = fexp2(sacc[i][2 * ksl + 1][2]);
                const float p7 = fexp2(sacc[i][2 * ksl + 1][3]);
                lrow[i] += ((p0 + p1) + (p2 + p3)) + ((p4 + p5) + (p6 + p7));
                union { bf16x8 v; uint32_t u[4]; } c;
                c.u[0] = pk2bf(p0, p1);
                c.u[1] = pk2bf(p2, p3);
                c.u[2] = pk2bf(p4, p5);
                c.u[3] = pk2bf(p6, p7);
                pa[i] = c.v;
            }
            __builtin_amdgcn_s_setprio(1);
#pragma unroll
            for (int n = 0; n < 4; ++n) {
                const int pc = (gs * 4 + quad) ^ lm;
                bf16x8 vf = *(const bf16x8*)(Vb + (n * 16 + lm) * 128 + pc * 8);
#pragma unroll
                for (int i = 0; i < 2; ++i)
                    oacc[i][n] = __builtin_amdgcn_mfma_f32_16x16x32_bf16(pa[i], vf, oacc[i][n], 0, 0, 0);
            }
            __builtin_amdgcn_s_setprio(0);
        }
    };

    stage(0, 0);
    int cur = 0;
#pragma unroll 1
    for (int jt = 0; jt < 15; ++jt) {
        stage((jt + 1) * 128, cur ^ 1);
        asm volatile("s_waitcnt vmcnt(4)" ::: "memory");
        __builtin_amdgcn_sched_barrier(0);
        __builtin_amdgcn_s_barrier();
        compute(jt * 128, cur);
        __builtin_amdgcn_s_barrier();
        cur ^= 1;
    }
    asm volatile("s_waitcnt vmcnt(0)" ::: "memory");
    __builtin_amdgcn_sched_barrier(0);
    __builtin_amdgcn_s_barrier();
    compute(15 * 128, cur);

    // combine key-half partials via LDS
    __syncthreads();
    f32x4* red = (f32x4*)&lsAll[0][0];
    if (wid >= 4) {
        const int base = ((wid - 4) * 64 + lane) * 9;
#pragma unroll
        for (int i = 0; i < 2; ++i)
#pragma unroll
            for (int n = 0; n < 4; ++n) red[base + i * 4 + n] = oacc[i][n];
        red[base + 8] = (f32x4){lrow[0], lrow[1], 0.f, 0.f};
    }
    __syncthreads();
    if (wid < 4) {
        const int base = (wid * 64 + lane) * 9;
#pragma unroll
        for (int i = 0; i < 2; ++i)
#pragma unroll
            for (int n = 0; n < 4; ++n) oacc[i][n] += red[base + i * 4 + n];
        const f32x4 lr = red[base + 8];
        lrow[0] += lr[0]; lrow[1] += lr[1];

#pragma unroll
        for (int i = 0; i < 2; ++i) {
            float l = lrow[i];
            l += __shfl_xor(l, 16);
            l += __shfl_xor(l, 32);
            const float inv = 1.f / (l + 1e-30f);
#pragma unroll
            for (int r = 0; r < 4; ++r) {
                const float invr = __shfl(inv, quad * 4 + r, 16);
                const int s = q0 + wid * 32 + i * 16 + quad * 4 + r;
#pragma unroll
                for (int n = 0; n < 4; ++n)
                    Out[(size_t)(b * 2048 + s) * 512 + h * 64 + n * 16 + lm] = f2bf(oacc[i][n][r] * invr);
            }
        }
    }
}

// ---------------------------------------------------------------------------
// Launch — fp32 in, fp32 out; ws peak 37 MiB; 6 dispatches.
// ---------------------------------------------------------------------------
extern "C" void kernel_launch(void* const* d_in, const int* in_sizes, int n_in,
                              void* d_out, int out_size, void* d_ws, size_t ws_size,
                              hipStream_t stream)
{
    const float* x  = (const float*)d_in[0];
    const float* W1 = (const float*)d_in[1];
    const float* b1 = (const float*)d_in[2];
    const float* W2 = (const float*)d_in[3];
    const float* b2 = (const float*)d_in[4];
    const float* Wq = (const float*)d_in[5];
    const float* bq = (const float*)d_in[6];
    const float* Wk = (const float*)d_in[7];
    const float* bk = (const float*)d_in[8];
    const float* Wv = (const float*)d_in[9];
    const float* bv = (const float*)d_in[10];
    const float* Wo = (const float*)d_in[11];
    const float* bo = (const float*)d_in[12];
    (void)in_sizes; (void)n_in; (void)out_size; (void)ws_size;

    char* ws = (char*)d_ws;
    const size_t MiB = 1024 * 1024;
    uint16_t* xb    = (uint16_t*)(ws + 0);                       // 8 MiB [dead after G1]
    uint16_t* W1T   = (uint16_t*)(ws + 8 * MiB);                 // 1 MiB  [1024][512]
    uint16_t* W2T   = (uint16_t*)(ws + 9 * MiB);                 // 1 MiB  [512][1024]
    uint16_t* WqkvT = (uint16_t*)(ws + 10 * MiB);                // 1.5 MiB [1536][512]
    uint16_t* WoT   = (uint16_t*)(ws + 11 * MiB + 512 * 1024);   // 0.5 MiB [512][512]
    uint16_t* bbase = (uint16_t*)(ws + 12 * MiB);                // 3584 u16
    uint16_t* b1b = bbase, *b2b = bbase + 1024, *bqb = bbase + 1536;
    uint16_t* bkb = bbase + 2048, *bvb = bbase + 2560, *bob = bbase + 3072;
    uint16_t* xm1   = (uint16_t*)(ws + 13 * MiB);                // 16 MiB [13,29)
    uint16_t* xm    = (uint16_t*)(ws + 29 * MiB);                //  8 MiB [29,37)
    uint16_t* qk    = xm1;   // aliases xm1 (dead after G2)
    uint16_t* att   = xm;    // aliases xm  (dead after QKV gemm)
    uint16_t* Vt    = xb;    // aliases xb  (dead after G1)

    prep_all<<<6158, dim3(32, 8), 0, stream>>>(x, W1, W2, Wq, Wk, Wv, Wo,
                                               b1, b2, bq, bk, bv, bo,
                                               W1T, W2T, WqkvT, WoT, xb, bbase);

    gemm_k64<1,0><<<dim3(8, 128),  256, 0, stream>>>(xb,  W1T, b1b, xm1, 8192, 1024, 512);
    gemm_k32<0,0><<<dim3(4, 256),  256, 0, stream>>>(xm1, W2T, b2b, xm,  8192, 512, 1024);
    gemm_qkv64   <<<dim3(12, 128), 256, 0, stream>>>(xm, WqkvT, bqb, bkb, bvb, qk, Vt);
    attn_k       <<<dim3(16, 32),  512, 0, stream>>>(qk, Vt, att);
    gemm_k32<0,1><<<dim3(4, 256),  256, 0, stream>>>(att, WoT, bob, d_out, 8192, 512, 512);
}